// Round 2
// baseline (209.478 us; speedup 1.0000x reference)
//
#include <hip/hip_runtime.h>

typedef unsigned short ushort_t;
using bf16x8 = __attribute__((ext_vector_type(8))) short;
using f32x16 = __attribute__((ext_vector_type(16))) float;

#define KT 27
#define NV 65536

__device__ inline unsigned short f2bf(float f) {
  unsigned int u = __builtin_bit_cast(unsigned int, f);
  u += 0x7fffu + ((u >> 16) & 1u);
  return (unsigned short)(u >> 16);
}
__device__ inline float b2f(ushort_t u) {
  unsigned int x = ((unsigned int)u) << 16;
  return __builtin_bit_cast(float, x);
}

// compile-time loop: forces every index to be constexpr so pipeline arrays
// stay in registers (runtime-indexed ext_vector arrays demote to scratch).
template <int I, int N, typename F>
__device__ __forceinline__ void static_for(F&& f) {
  if constexpr (I < N) {
    f.template operator()<I>();
    static_for<I + 1, N>(static_cast<F&&>(f));
  }
}

// merged prep: statsp+zrow zero (block 0), x fp32->bf16 (blocks 0..4095),
// W1,W2 [k][c][d] -> per-lane MFMA B frags (blocks 4096..5823)
// Wf[(k*8 + ks*2 + ct)*512 + l*8 + j] = bf16(W[k][ks*16 + (l>>5)*8 + j][ct*32 + (l&31)])
__global__ __launch_bounds__(256) void k_prep(const float* __restrict__ x,
                                              const float* __restrict__ W1,
                                              const float* __restrict__ W2,
                                              ushort_t* __restrict__ xb,
                                              ushort_t* __restrict__ Wf1,
                                              ushort_t* __restrict__ Wf2,
                                              float* __restrict__ statsp) {
  int b = blockIdx.x;
  int t = threadIdx.x;
  if (b == 0) {                    // 256 stats floats + 256 floats of zero-row pad
    statsp[t] = 0.f;               // convs run after this dispatch
    statsp[256 + t] = 0.f;         // zrow: gather target for inactive taps
  }
  if (b < 4096) {
    int i = b * 256 + t;  // float4 index
    float4 v = ((const float4*)x)[i];
    ushort4 o;
    o.x = f2bf(v.x); o.y = f2bf(v.y); o.z = f2bf(v.z); o.w = f2bf(v.w);
    ((ushort4*)xb)[i] = o;
  } else {
    int e = (b - 4096) * 256 + t;  // < 442368
    const float* W = W1; ushort_t* Wf = Wf1;
    if (e >= 221184) { e -= 221184; W = W2; Wf = Wf2; }
    int j = e & 7, l = (e >> 3) & 63, u = (e >> 9) & 7, k = e >> 12;
    int ks = u >> 1, ct = u & 1;
    int c = ks * 16 + (l >> 5) * 8 + j;
    int d = ct * 32 + (l & 31);
    Wf[e] = f2bf(W[(k << 12) + (c << 6) + d]);
  }
}

// Gather-GEMM conv, 32x32x16 MFMA, BARRIER-FREE K-loop, ZERO A-staging.
// block = 256 thr = 4 fully independent waves; wave w owns voxels wbase..wbase+31.
// A fragments are gathered DIRECTLY from global into MFMA layout:
//   lane needs row (lane&31) channels [ks*16 + (lane>>5)*8, +8) -> one 16B load,
//   i.e. global -> VGPR -> MFMA with no LDS round-trip at all.
// Inactive taps (idx<0) gather from a 128B zero row instead (pointer cndmask).
// Pipeline: A prefetched 4 taps ahead (ring of 5 reg slots), B double-buffered.
// K-loop is static_for-unrolled: ALL array indices are constexpr -> pipeline
// state provably lives in VGPRs (VGPR_Count must read ~200, not 44).
// Only LDS: per-wave rulebook rows + stats reduce (15.9 KB/block).
template<bool OBF16>
__global__ __launch_bounds__(256, 2) void k_conv(const ushort_t* __restrict__ src,  // [N][64] bf16
                                                 const int* __restrict__ nbr,       // [N][27]
                                                 const ushort_t* __restrict__ Wf,
                                                 const ushort_t* __restrict__ zrow, // 128B of zeros
                                                 void* __restrict__ houtv,          // [N][64]
                                                 float* __restrict__ gsum,
                                                 float* __restrict__ gsq) {
  __shared__ int nb_l[4][32 * KT];                 // per-wave rulebook rows, 13.8 KB
  __shared__ float red[2][4][64];                  // stats reduce, 2 KB

  const int t = threadIdx.x;
  const int lane = t & 63;
  const int w = t >> 6;
  const int hh = lane >> 5;
  const int r31 = lane & 31;
  const int wbase = blockIdx.x * 128 + w * 32;

  int* nbw = &nb_l[w][0];
  {
    const int* nbg = nbr + wbase * KT;
    for (int e = lane; e < 32 * KT; e += 64) nbw[e] = nbg[e];  // wave-local: no barrier
  }

  f32x16 acc0 = {0,0,0,0,0,0,0,0,0,0,0,0,0,0,0,0};
  f32x16 acc1 = {0,0,0,0,0,0,0,0,0,0,0,0,0,0,0,0};

  bf16x8 aF[5][4];   // ring-5 of taps, 4 K-slices each (80 VGPRs)
  bf16x8 bB[2][8];   // double-buffered B frags (64 VGPRs)

  const ushort_t* srcl = src + hh * 8;   // lane's K-half offset folded into base
  const ushort_t* zl = zrow + hh * 8;

  // A frag for tap k: row r31, channels ks*16 + hh*8 .. +8  (one dwordx4 each)
  auto ldA = [&](int k, bf16x8* a) {
    int idx = nbw[r31 * KT + k];
    const ushort_t* p = (idx >= 0) ? (srcl + ((long)idx << 6)) : zl;
#pragma unroll
    for (int ks = 0; ks < 4; ++ks) a[ks] = *(const bf16x8*)(p + ks * 16);
  };
  auto ldB = [&](int k, bf16x8* b) {
    const ushort_t* p = Wf + k * 4096 + lane * 8;
#pragma unroll
    for (int u = 0; u < 8; ++u) b[u] = *(const bf16x8*)(p + u * 512);
  };
  auto compute = [&](const bf16x8* a, const bf16x8* b) {
#pragma unroll
    for (int ks = 0; ks < 4; ++ks) {
      acc0 = __builtin_amdgcn_mfma_f32_32x32x16_bf16(a[ks], b[ks * 2 + 0], acc0, 0, 0, 0);
      acc1 = __builtin_amdgcn_mfma_f32_32x32x16_bf16(a[ks], b[ks * 2 + 1], acc1, 0, 0, 0);
    }
  };

  // prologue: A taps 0..3 in flight, B tap 0
  ldA(0, aF[0]); ldA(1, aF[1]); ldA(2, aF[2]); ldA(3, aF[3]);
  ldB(0, bB[0]);

  // invariant at iter k: aF[k%5] = tap k, bB[k&1] = B(k); prefetch slot
  // (k+4)%5 == (k-1)%5 was consumed last iteration -> never clobbers live data.
  static_for<0, KT>([&]<int k>() {
    if constexpr (k + 4 < KT) ldA(k + 4, aF[(k + 4) % 5]);   // 4-tap latency slack
    if constexpr (k + 1 < KT) ldB(k + 1, bB[(k + 1) & 1]);   // 1-tap slack (L2-hot)
    compute(aF[k % 5], bB[k & 1]);
  });

  // epilogue: store h + fused per-channel stats
  // C/D (32x32): col = lane&31, row = (reg&3) + 8*(reg>>2) + 4*(lane>>5)
  const int orow0 = wbase + (hh << 2);
  float s0 = 0.f, q0 = 0.f, s1 = 0.f, q1 = 0.f;
#pragma unroll
  for (int reg = 0; reg < 16; ++reg) {
    int row = orow0 + (reg & 3) + 8 * (reg >> 2);
    float v0 = acc0[reg], v1 = acc1[reg];
    if (OBF16) {
      ushort_t* ho = (ushort_t*)houtv;
      ho[row * 64 + r31] = f2bf(v0);
      ho[row * 64 + 32 + r31] = f2bf(v1);
    } else {
      float* ho = (float*)houtv;
      ho[row * 64 + r31] = v0;
      ho[row * 64 + 32 + r31] = v1;
    }
    s0 += v0; q0 += v0 * v0;
    s1 += v1; q1 += v1 * v1;
  }
  s0 += __shfl_xor(s0, 32, 64); q0 += __shfl_xor(q0, 32, 64);
  s1 += __shfl_xor(s1, 32, 64); q1 += __shfl_xor(q1, 32, 64);
  if (hh == 0) {
    red[0][w][r31] = s0; red[0][w][32 + r31] = s1;
    red[1][w][r31] = q0; red[1][w][32 + r31] = q1;
  }
  __syncthreads();   // only barrier in the kernel
  if (t < 128) {
    int which = t >> 6, c = t & 63;
    float v = red[which][0][c] + red[which][1][c] + red[which][2][c] + red[which][3][c];
    atomicAdd((which ? gsq : gsum) + c, v);
  }
}

// BN1 (inline params from raw stats) + ReLU on bf16 h1, writes bf16 for conv2's gather
__global__ __launch_bounds__(256) void k_bn_relu(const ushort_t* __restrict__ h,
                                                 const float* __restrict__ gsum,
                                                 const float* __restrict__ gsq,
                                                 const float* __restrict__ gamma,
                                                 const float* __restrict__ beta,
                                                 ushort_t* __restrict__ ob) {
  __shared__ float sc[64], sh[64];
  int t = threadIdx.x;
  if (t < 64) {
    float mean = gsum[t] * (1.f / NV);
    float var = gsq[t] * (1.f / NV) - mean * mean;
    float rs = rsqrtf(var + 1e-5f);
    float s = gamma[t] * rs;
    sc[t] = s;
    sh[t] = beta[t] - mean * s;
  }
  __syncthreads();
  int i = blockIdx.x * 256 + t;    // uint4 index = 8 bf16
  int c0 = (i & 7) * 8;
  uint4 v = ((const uint4*)h)[i];
  const ushort_t* pu = (const ushort_t*)&v;
  uint4 o;
  ushort_t* po = (ushort_t*)&o;
#pragma unroll
  for (int n = 0; n < 8; ++n)
    po[n] = f2bf(fmaxf(0.f, b2f(pu[n]) * sc[c0 + n] + sh[c0 + n]));
  ((uint4*)ob)[i] = o;
}

// BN2 (inline params) + residual + ReLU, fp32 out
__global__ __launch_bounds__(256) void k_final(const float* __restrict__ h,
                                               const float* __restrict__ x,
                                               const float* __restrict__ gsum,
                                               const float* __restrict__ gsq,
                                               const float* __restrict__ gamma,
                                               const float* __restrict__ beta,
                                               float* __restrict__ out) {
  __shared__ float sc[64], sh[64];
  int t = threadIdx.x;
  if (t < 64) {
    float mean = gsum[t] * (1.f / NV);
    float var = gsq[t] * (1.f / NV) - mean * mean;
    float rs = rsqrtf(var + 1e-5f);
    float s = gamma[t] * rs;
    sc[t] = s;
    sh[t] = beta[t] - mean * s;
  }
  __syncthreads();
  int i = blockIdx.x * 256 + t;
  int c0 = (i << 2) & 63;
  float4 v = ((const float4*)h)[i];
  float4 xv = ((const float4*)x)[i];
  float4 o;
  o.x = fmaxf(0.f, v.x * sc[c0]     + sh[c0]     + xv.x);
  o.y = fmaxf(0.f, v.y * sc[c0 + 1] + sh[c0 + 1] + xv.y);
  o.z = fmaxf(0.f, v.z * sc[c0 + 2] + sh[c0 + 2] + xv.z);
  o.w = fmaxf(0.f, v.w * sc[c0 + 3] + sh[c0 + 3] + xv.w);
  ((float4*)out)[i] = o;
}

extern "C" void kernel_launch(void* const* d_in, const int* in_sizes, int n_in,
                              void* d_out, int out_size, void* d_ws, size_t ws_size,
                              hipStream_t stream) {
  const float* x   = (const float*)d_in[0];
  const int*   nbr = (const int*)d_in[1];
  const float* W1  = (const float*)d_in[2];
  const float* g1  = (const float*)d_in[3];
  const float* b1  = (const float*)d_in[4];
  const float* W2  = (const float*)d_in[5];
  const float* g2  = (const float*)d_in[6];
  const float* b2  = (const float*)d_in[7];
  float* out = (float*)d_out;
  char* ws = (char*)d_ws;

  // workspace layout (bytes, 256-aligned), total ~42.8 MB (+2KB stats/zero pad)
  ushort_t* xb     = (ushort_t*)(ws);               // 8,388,608
  ushort_t* h1pre  = (ushort_t*)(ws + 8388608);     // 8,388,608 (bf16, pre-BN)
  ushort_t* h1post = (ushort_t*)(ws + 16777216);    // 8,388,608 (bf16, post-BN+ReLU)
  ushort_t* Wf1    = (ushort_t*)(ws + 25165824);    // 442,368
  ushort_t* Wf2    = (ushort_t*)(ws + 25608192);    // 442,368
  float*    h2raw  = (float*)(ws + 26050560);       // 16,777,216
  float*    statsp = (float*)(ws + 42827776);       // 512 floats (stats + zero row)
  float *gsum1 = statsp, *gsq1 = statsp + 64, *gsum2 = statsp + 128, *gsq2 = statsp + 192;
  const ushort_t* zrow = (const ushort_t*)(statsp + 256);  // 1KB of zeros

  k_prep<<<5824, 256, 0, stream>>>(x, W1, W2, xb, Wf1, Wf2, statsp);

  k_conv<true><<<512, 256, 0, stream>>>(xb, nbr, Wf1, zrow, (void*)h1pre, gsum1, gsq1);
  k_bn_relu<<<2048, 256, 0, stream>>>(h1pre, gsum1, gsq1, g1, b1, h1post);
  k_conv<false><<<512, 256, 0, stream>>>(h1post, nbr, Wf2, zrow, (void*)h2raw, gsum2, gsq2);

  k_final<<<4096, 256, 0, stream>>>(h2raw, x, gsum2, gsq2, g2, b2, out);
}

// Round 3
// 208.850 us; speedup vs baseline: 1.0030x; 1.0030x over previous
//
#include <hip/hip_runtime.h>

typedef unsigned short ushort_t;
using bf16x8 = __attribute__((ext_vector_type(8))) short;
using f32x16 = __attribute__((ext_vector_type(16))) float;

#define KT 27
#define NV 65536

__device__ inline unsigned short f2bf(float f) {
  unsigned int u = __builtin_bit_cast(unsigned int, f);
  u += 0x7fffu + ((u >> 16) & 1u);
  return (unsigned short)(u >> 16);
}
__device__ inline float b2f(ushort_t u) {
  unsigned int x = ((unsigned int)u) << 16;
  return __builtin_bit_cast(float, x);
}

// compile-time loop: every iteration index is constexpr.
template <int I, int N, typename F>
__device__ __forceinline__ void static_for(F&& f) {
  if constexpr (I < N) {
    f.template operator()<I>();
    static_for<I + 1, N>(static_cast<F&&>(f));
  }
}

// merged prep: statsp+zrow zero (block 0), x fp32->bf16 (blocks 0..4095),
// W1,W2 [k][c][d] -> per-lane MFMA B frags (blocks 4096..5823)
// Wf[(k*8 + ks*2 + ct)*512 + l*8 + j] = bf16(W[k][ks*16 + (l>>5)*8 + j][ct*32 + (l&31)])
__global__ __launch_bounds__(256) void k_prep(const float* __restrict__ x,
                                              const float* __restrict__ W1,
                                              const float* __restrict__ W2,
                                              ushort_t* __restrict__ xb,
                                              ushort_t* __restrict__ Wf1,
                                              ushort_t* __restrict__ Wf2,
                                              float* __restrict__ statsp) {
  int b = blockIdx.x;
  int t = threadIdx.x;
  if (b == 0) {                    // 256 stats floats + 256 floats of zero-row pad
    statsp[t] = 0.f;               // convs run after this dispatch
    statsp[256 + t] = 0.f;         // zrow: gather target for inactive taps
  }
  if (b < 4096) {
    int i = b * 256 + t;  // float4 index
    float4 v = ((const float4*)x)[i];
    ushort4 o;
    o.x = f2bf(v.x); o.y = f2bf(v.y); o.z = f2bf(v.z); o.w = f2bf(v.w);
    ((ushort4*)xb)[i] = o;
  } else {
    int e = (b - 4096) * 256 + t;  // < 442368
    const float* W = W1; ushort_t* Wf = Wf1;
    if (e >= 221184) { e -= 221184; W = W2; Wf = Wf2; }
    int j = e & 7, l = (e >> 3) & 63, u = (e >> 9) & 7, k = e >> 12;
    int ks = u >> 1, ct = u & 1;
    int c = ks * 16 + (l >> 5) * 8 + j;
    int d = ct * 32 + (l & 31);
    Wf[e] = f2bf(W[(k << 12) + (c << 6) + d]);
  }
}

// Gather-GEMM conv, 32x32x16 MFMA, BARRIER-FREE K-loop, ZERO A-staging.
// block = 256 thr = 4 fully independent waves; wave w owns voxels wbase..wbase+31.
// A fragments are gathered DIRECTLY from global into MFMA layout:
//   lane needs row (lane&31) channels [ks*16 + (lane>>5)*8, +8) -> one 16B load.
// Pipeline state is NAMED STRUCT VALUES ONLY (A0..A5, B0/B1) — no arrays, no
// address-taken, no runtime indexing -> provably SSA/VGPR-resident. Rounds 1-2
// used pointer-passed arrays which demoted to scratch (VGPR_Count read 40-44;
// per-tap chain became gather->scratch->MFMA ~5k cy). The tell this version
// works: VGPR_Count ~200.
// A prefetched 5 taps ahead (ring-6), B double-buffered.
// Only LDS: per-wave rulebook rows + stats reduce (15.9 KB/block).
template<bool OBF16>
__global__ __launch_bounds__(256, 2) void k_conv(const ushort_t* __restrict__ src,  // [N][64] bf16
                                                 const int* __restrict__ nbr,       // [N][27]
                                                 const ushort_t* __restrict__ Wf,
                                                 const ushort_t* __restrict__ zrow, // 128B of zeros
                                                 void* __restrict__ houtv,          // [N][64]
                                                 float* __restrict__ gsum,
                                                 float* __restrict__ gsq) {
  __shared__ int nb_l[4][32 * KT];                 // per-wave rulebook rows, 13.8 KB
  __shared__ float red[2][4][64];                  // stats reduce, 2 KB

  const int t = threadIdx.x;
  const int lane = t & 63;
  const int w = t >> 6;
  const int hh = lane >> 5;
  const int r31 = lane & 31;
  const int wbase = blockIdx.x * 128 + w * 32;

  int* nbw = &nb_l[w][0];
  {
    const int* nbg = nbr + wbase * KT;
    for (int e = lane; e < 32 * KT; e += 64) nbw[e] = nbg[e];  // wave-local: no barrier
  }

  f32x16 acc0 = {0,0,0,0,0,0,0,0,0,0,0,0,0,0,0,0};
  f32x16 acc1 = {0,0,0,0,0,0,0,0,0,0,0,0,0,0,0,0};

  struct ATap { bf16x8 v0, v1, v2, v3; };              // 16 VGPRs, by-value only
  struct BTap { bf16x8 b0, b1, b2, b3, b4, b5, b6, b7; };  // 32 VGPRs, by-value only

  const ushort_t* srcl = src + hh * 8;   // lane's K-half offset folded into base
  const ushort_t* zl = zrow + hh * 8;

  // A frag for tap k: row r31, channels ks*16 + hh*8 .. +8  (one dwordx4 each)
  auto ldA = [&](int k) -> ATap {
    int idx = nbw[r31 * KT + k];
    const ushort_t* p = (idx >= 0) ? (srcl + ((long)idx << 6)) : zl;
    ATap a;
    a.v0 = *(const bf16x8*)(p);
    a.v1 = *(const bf16x8*)(p + 16);
    a.v2 = *(const bf16x8*)(p + 32);
    a.v3 = *(const bf16x8*)(p + 48);
    return a;
  };
  auto ldB = [&](int k) -> BTap {
    const ushort_t* p = Wf + k * 4096 + lane * 8;
    BTap b;
    b.b0 = *(const bf16x8*)(p);
    b.b1 = *(const bf16x8*)(p + 512);
    b.b2 = *(const bf16x8*)(p + 1024);
    b.b3 = *(const bf16x8*)(p + 1536);
    b.b4 = *(const bf16x8*)(p + 2048);
    b.b5 = *(const bf16x8*)(p + 2560);
    b.b6 = *(const bf16x8*)(p + 3072);
    b.b7 = *(const bf16x8*)(p + 3584);
    return b;
  };
  auto compute = [&](ATap a, BTap b) {
    acc0 = __builtin_amdgcn_mfma_f32_32x32x16_bf16(a.v0, b.b0, acc0, 0, 0, 0);
    acc1 = __builtin_amdgcn_mfma_f32_32x32x16_bf16(a.v0, b.b1, acc1, 0, 0, 0);
    acc0 = __builtin_amdgcn_mfma_f32_32x32x16_bf16(a.v1, b.b2, acc0, 0, 0, 0);
    acc1 = __builtin_amdgcn_mfma_f32_32x32x16_bf16(a.v1, b.b3, acc1, 0, 0, 0);
    acc0 = __builtin_amdgcn_mfma_f32_32x32x16_bf16(a.v2, b.b4, acc0, 0, 0, 0);
    acc1 = __builtin_amdgcn_mfma_f32_32x32x16_bf16(a.v2, b.b5, acc1, 0, 0, 0);
    acc0 = __builtin_amdgcn_mfma_f32_32x32x16_bf16(a.v3, b.b6, acc0, 0, 0, 0);
    acc1 = __builtin_amdgcn_mfma_f32_32x32x16_bf16(a.v3, b.b7, acc1, 0, 0, 0);
  };

  // prologue: A taps 0..4 in flight (ring-6, depth-5 prefetch), B tap 0
  ATap A0 = ldA(0), A1 = ldA(1), A2 = ldA(2), A3 = ldA(3), A4 = ldA(4), A5;
  BTap B0 = ldB(0), B1;

  // invariant at iter k: slot k%6 holds tap k, B(k&1) holds tap k.
  // prefetch slot (k+5)%6 == (k-1)%6 was consumed last iteration.
  static_for<0, KT>([&]<int k>() {
    if constexpr (k + 5 < KT) {
      ATap tmp = ldA(k + 5);
      constexpr int s = (k + 5) % 6;
      if constexpr (s == 0) A0 = tmp;
      else if constexpr (s == 1) A1 = tmp;
      else if constexpr (s == 2) A2 = tmp;
      else if constexpr (s == 3) A3 = tmp;
      else if constexpr (s == 4) A4 = tmp;
      else A5 = tmp;
    }
    if constexpr (k + 1 < KT) {
      BTap tmp = ldB(k + 1);
      if constexpr (((k + 1) & 1) == 0) B0 = tmp; else B1 = tmp;
    }
    constexpr int c = k % 6;
    if constexpr (c == 0) { if constexpr ((k & 1) == 0) compute(A0, B0); else compute(A0, B1); }
    else if constexpr (c == 1) { if constexpr ((k & 1) == 0) compute(A1, B0); else compute(A1, B1); }
    else if constexpr (c == 2) { if constexpr ((k & 1) == 0) compute(A2, B0); else compute(A2, B1); }
    else if constexpr (c == 3) { if constexpr ((k & 1) == 0) compute(A3, B0); else compute(A3, B1); }
    else if constexpr (c == 4) { if constexpr ((k & 1) == 0) compute(A4, B0); else compute(A4, B1); }
    else { if constexpr ((k & 1) == 0) compute(A5, B0); else compute(A5, B1); }
  });

  // epilogue: store h + fused per-channel stats
  // C/D (32x32): col = lane&31, row = (reg&3) + 8*(reg>>2) + 4*(lane>>5)
  const int orow0 = wbase + (hh << 2);
  float s0 = 0.f, q0 = 0.f, s1 = 0.f, q1 = 0.f;
#pragma unroll
  for (int reg = 0; reg < 16; ++reg) {
    int row = orow0 + (reg & 3) + 8 * (reg >> 2);
    float v0 = acc0[reg], v1 = acc1[reg];
    if (OBF16) {
      ushort_t* ho = (ushort_t*)houtv;
      ho[row * 64 + r31] = f2bf(v0);
      ho[row * 64 + 32 + r31] = f2bf(v1);
    } else {
      float* ho = (float*)houtv;
      ho[row * 64 + r31] = v0;
      ho[row * 64 + 32 + r31] = v1;
    }
    s0 += v0; q0 += v0 * v0;
    s1 += v1; q1 += v1 * v1;
  }
  s0 += __shfl_xor(s0, 32, 64); q0 += __shfl_xor(q0, 32, 64);
  s1 += __shfl_xor(s1, 32, 64); q1 += __shfl_xor(q1, 32, 64);
  if (hh == 0) {
    red[0][w][r31] = s0; red[0][w][32 + r31] = s1;
    red[1][w][r31] = q0; red[1][w][32 + r31] = q1;
  }
  __syncthreads();   // only barrier in the kernel
  if (t < 128) {
    int which = t >> 6, c = t & 63;
    float v = red[which][0][c] + red[which][1][c] + red[which][2][c] + red[which][3][c];
    atomicAdd((which ? gsq : gsum) + c, v);
  }
}

// BN1 (inline params from raw stats) + ReLU on bf16 h1, writes bf16 for conv2's gather
__global__ __launch_bounds__(256) void k_bn_relu(const ushort_t* __restrict__ h,
                                                 const float* __restrict__ gsum,
                                                 const float* __restrict__ gsq,
                                                 const float* __restrict__ gamma,
                                                 const float* __restrict__ beta,
                                                 ushort_t* __restrict__ ob) {
  __shared__ float sc[64], sh[64];
  int t = threadIdx.x;
  if (t < 64) {
    float mean = gsum[t] * (1.f / NV);
    float var = gsq[t] * (1.f / NV) - mean * mean;
    float rs = rsqrtf(var + 1e-5f);
    float s = gamma[t] * rs;
    sc[t] = s;
    sh[t] = beta[t] - mean * s;
  }
  __syncthreads();
  int i = blockIdx.x * 256 + t;    // uint4 index = 8 bf16
  int c0 = (i & 7) * 8;
  uint4 v = ((const uint4*)h)[i];
  const ushort_t* pu = (const ushort_t*)&v;
  uint4 o;
  ushort_t* po = (ushort_t*)&o;
#pragma unroll
  for (int n = 0; n < 8; ++n)
    po[n] = f2bf(fmaxf(0.f, b2f(pu[n]) * sc[c0 + n] + sh[c0 + n]));
  ((uint4*)ob)[i] = o;
}

// BN2 (inline params) + residual + ReLU, fp32 out
__global__ __launch_bounds__(256) void k_final(const float* __restrict__ h,
                                               const float* __restrict__ x,
                                               const float* __restrict__ gsum,
                                               const float* __restrict__ gsq,
                                               const float* __restrict__ gamma,
                                               const float* __restrict__ beta,
                                               float* __restrict__ out) {
  __shared__ float sc[64], sh[64];
  int t = threadIdx.x;
  if (t < 64) {
    float mean = gsum[t] * (1.f / NV);
    float var = gsq[t] * (1.f / NV) - mean * mean;
    float rs = rsqrtf(var + 1e-5f);
    float s = gamma[t] * rs;
    sc[t] = s;
    sh[t] = beta[t] - mean * s;
  }
  __syncthreads();
  int i = blockIdx.x * 256 + t;
  int c0 = (i << 2) & 63;
  float4 v = ((const float4*)h)[i];
  float4 xv = ((const float4*)x)[i];
  float4 o;
  o.x = fmaxf(0.f, v.x * sc[c0]     + sh[c0]     + xv.x);
  o.y = fmaxf(0.f, v.y * sc[c0 + 1] + sh[c0 + 1] + xv.y);
  o.z = fmaxf(0.f, v.z * sc[c0 + 2] + sh[c0 + 2] + xv.z);
  o.w = fmaxf(0.f, v.w * sc[c0 + 3] + sh[c0 + 3] + xv.w);
  ((float4*)out)[i] = o;
}

extern "C" void kernel_launch(void* const* d_in, const int* in_sizes, int n_in,
                              void* d_out, int out_size, void* d_ws, size_t ws_size,
                              hipStream_t stream) {
  const float* x   = (const float*)d_in[0];
  const int*   nbr = (const int*)d_in[1];
  const float* W1  = (const float*)d_in[2];
  const float* g1  = (const float*)d_in[3];
  const float* b1  = (const float*)d_in[4];
  const float* W2  = (const float*)d_in[5];
  const float* g2  = (const float*)d_in[6];
  const float* b2  = (const float*)d_in[7];
  float* out = (float*)d_out;
  char* ws = (char*)d_ws;

  // workspace layout (bytes, 256-aligned), total ~42.8 MB (+2KB stats/zero pad)
  ushort_t* xb     = (ushort_t*)(ws);               // 8,388,608
  ushort_t* h1pre  = (ushort_t*)(ws + 8388608);     // 8,388,608 (bf16, pre-BN)
  ushort_t* h1post = (ushort_t*)(ws + 16777216);    // 8,388,608 (bf16, post-BN+ReLU)
  ushort_t* Wf1    = (ushort_t*)(ws + 25165824);    // 442,368
  ushort_t* Wf2    = (ushort_t*)(ws + 25608192);    // 442,368
  float*    h2raw  = (float*)(ws + 26050560);       // 16,777,216
  float*    statsp = (float*)(ws + 42827776);       // 512 floats (stats + zero row)
  float *gsum1 = statsp, *gsq1 = statsp + 64, *gsum2 = statsp + 128, *gsq2 = statsp + 192;
  const ushort_t* zrow = (const ushort_t*)(statsp + 256);  // 1KB of zeros

  k_prep<<<5824, 256, 0, stream>>>(x, W1, W2, xb, Wf1, Wf2, statsp);

  k_conv<true><<<512, 256, 0, stream>>>(xb, nbr, Wf1, zrow, (void*)h1pre, gsum1, gsq1);
  k_bn_relu<<<2048, 256, 0, stream>>>(h1pre, gsum1, gsq1, g1, b1, h1post);
  k_conv<false><<<512, 256, 0, stream>>>(h1post, nbr, Wf2, zrow, (void*)h2raw, gsum2, gsq2);

  k_final<<<4096, 256, 0, stream>>>(h2raw, x, gsum2, gsq2, g2, b2, out);
}

// Round 4
// 184.117 us; speedup vs baseline: 1.1377x; 1.1343x over previous
//
#include <hip/hip_runtime.h>

typedef unsigned short ushort_t;
using bf16x8 = __attribute__((ext_vector_type(8))) short;
using f32x16 = __attribute__((ext_vector_type(16))) float;

#define KT 27
#define NV 65536

__device__ inline unsigned short f2bf(float f) {
  unsigned int u = __builtin_bit_cast(unsigned int, f);
  u += 0x7fffu + ((u >> 16) & 1u);
  return (unsigned short)(u >> 16);
}
__device__ inline float b2f(ushort_t u) {
  unsigned int x = ((unsigned int)u) << 16;
  return __builtin_bit_cast(float, x);
}

// compile-time loop: every iteration index is constexpr.
template <int I, int N, typename F>
__device__ __forceinline__ void static_for(F&& f) {
  if constexpr (I < N) {
    f.template operator()<I>();
    static_for<I + 1, N>(static_cast<F&&>(f));
  }
}

// merged prep: statsp+zrow zero (block 0), x fp32->bf16 (blocks 0..4095),
// W1,W2 [k][c][d] -> per-lane MFMA B frags (blocks 4096..5823)
// Wf[(k*8 + ks*2 + ct)*512 + l*8 + j] = bf16(W[k][ks*16 + (l>>5)*8 + j][ct*32 + (l&31)])
__global__ __launch_bounds__(256) void k_prep(const float* __restrict__ x,
                                              const float* __restrict__ W1,
                                              const float* __restrict__ W2,
                                              ushort_t* __restrict__ xb,
                                              ushort_t* __restrict__ Wf1,
                                              ushort_t* __restrict__ Wf2,
                                              float* __restrict__ statsp) {
  int b = blockIdx.x;
  int t = threadIdx.x;
  if (b == 0) {                    // 256 stats floats + 256 floats of zero-row pad
    statsp[t] = 0.f;               // convs run after this dispatch
    statsp[256 + t] = 0.f;         // zrow: gather target for inactive taps
  }
  if (b < 4096) {
    int i = b * 256 + t;  // float4 index
    float4 v = ((const float4*)x)[i];
    ushort4 o;
    o.x = f2bf(v.x); o.y = f2bf(v.y); o.z = f2bf(v.z); o.w = f2bf(v.w);
    ((ushort4*)xb)[i] = o;
  } else {
    int e = (b - 4096) * 256 + t;  // < 442368
    const float* W = W1; ushort_t* Wf = Wf1;
    if (e >= 221184) { e -= 221184; W = W2; Wf = Wf2; }
    int j = e & 7, l = (e >> 3) & 63, u = (e >> 9) & 7, k = e >> 12;
    int ks = u >> 1, ct = u & 1;
    int c = ks * 16 + (l >> 5) * 8 + j;
    int d = ct * 32 + (l & 31);
    Wf[e] = f2bf(W[(k << 12) + (c << 6) + d]);
  }
}

// Gather-GEMM conv, 32x32x16 MFMA, BARRIER-FREE K-loop, ZERO A-staging.
// block = 256 thr = 4 fully independent waves; wave w owns voxels wbase..wbase+31.
// A fragments gathered DIRECTLY from global into MFMA layout (one 16B load per
// lane per k-slice); B frags register-direct from pre-swizzled Wf (L2-hot).
// KEY FIX (R4): amdgpu_waves_per_eu(2,2) pins occupancy at the grid-imposed
// 2 waves/EU. Without it the scheduler minimized register pressure chasing
// 8 waves/EU it can never get (grid=512 blocks), sinking every load to its
// use (VGPR_Count read 40, all prefetch destroyed, 59us). With max=2, holding
// ~200 VGPRs is free. The tell this works: VGPR_Count ~200.
// Pipeline: A prefetched 4 taps ahead (ring-5 named SSA slots), B dbuf.
// Only LDS: per-wave rulebook rows + stats reduce (15.9 KB/block).
template<bool OBF16>
__global__ __launch_bounds__(256)
__attribute__((amdgpu_waves_per_eu(2, 2)))
void k_conv(const ushort_t* __restrict__ src,  // [N][64] bf16
            const int* __restrict__ nbr,       // [N][27]
            const ushort_t* __restrict__ Wf,
            const ushort_t* __restrict__ zrow, // 128B of zeros
            void* __restrict__ houtv,          // [N][64]
            float* __restrict__ gsum,
            float* __restrict__ gsq) {
  __shared__ int nb_l[4][32 * KT];                 // per-wave rulebook rows, 13.8 KB
  __shared__ float red[2][4][64];                  // stats reduce, 2 KB

  const int t = threadIdx.x;
  const int lane = t & 63;
  const int w = t >> 6;
  const int hh = lane >> 5;
  const int r31 = lane & 31;
  const int wbase = blockIdx.x * 128 + w * 32;

  int* nbw = &nb_l[w][0];
  {
    const int* nbg = nbr + wbase * KT;
    for (int e = lane; e < 32 * KT; e += 64) nbw[e] = nbg[e];  // wave-local: no barrier
  }

  f32x16 acc0 = {0,0,0,0,0,0,0,0,0,0,0,0,0,0,0,0};
  f32x16 acc1 = {0,0,0,0,0,0,0,0,0,0,0,0,0,0,0,0};

  struct ATap { bf16x8 v0, v1, v2, v3; };              // 16 VGPRs, by-value only
  struct BTap { bf16x8 b0, b1, b2, b3, b4, b5, b6, b7; };  // 32 VGPRs, by-value only

  const ushort_t* srcl = src + hh * 8;   // lane's K-half offset folded into base
  const ushort_t* zl = zrow + hh * 8;

  // A frag for tap k: row r31, channels ks*16 + hh*8 .. +8  (one dwordx4 each)
  auto ldA = [&](int k) -> ATap {
    int idx = nbw[r31 * KT + k];
    const ushort_t* p = (idx >= 0) ? (srcl + ((long)idx << 6)) : zl;
    ATap a;
    a.v0 = *(const bf16x8*)(p);
    a.v1 = *(const bf16x8*)(p + 16);
    a.v2 = *(const bf16x8*)(p + 32);
    a.v3 = *(const bf16x8*)(p + 48);
    return a;
  };
  auto ldB = [&](int k) -> BTap {
    const ushort_t* p = Wf + k * 4096 + lane * 8;
    BTap b;
    b.b0 = *(const bf16x8*)(p);
    b.b1 = *(const bf16x8*)(p + 512);
    b.b2 = *(const bf16x8*)(p + 1024);
    b.b3 = *(const bf16x8*)(p + 1536);
    b.b4 = *(const bf16x8*)(p + 2048);
    b.b5 = *(const bf16x8*)(p + 2560);
    b.b6 = *(const bf16x8*)(p + 3072);
    b.b7 = *(const bf16x8*)(p + 3584);
    return b;
  };
  auto compute = [&](ATap a, BTap b) {
    acc0 = __builtin_amdgcn_mfma_f32_32x32x16_bf16(a.v0, b.b0, acc0, 0, 0, 0);
    acc1 = __builtin_amdgcn_mfma_f32_32x32x16_bf16(a.v0, b.b1, acc1, 0, 0, 0);
    acc0 = __builtin_amdgcn_mfma_f32_32x32x16_bf16(a.v1, b.b2, acc0, 0, 0, 0);
    acc1 = __builtin_amdgcn_mfma_f32_32x32x16_bf16(a.v1, b.b3, acc1, 0, 0, 0);
    acc0 = __builtin_amdgcn_mfma_f32_32x32x16_bf16(a.v2, b.b4, acc0, 0, 0, 0);
    acc1 = __builtin_amdgcn_mfma_f32_32x32x16_bf16(a.v2, b.b5, acc1, 0, 0, 0);
    acc0 = __builtin_amdgcn_mfma_f32_32x32x16_bf16(a.v3, b.b6, acc0, 0, 0, 0);
    acc1 = __builtin_amdgcn_mfma_f32_32x32x16_bf16(a.v3, b.b7, acc1, 0, 0, 0);
  };

  // prologue: A taps 0..3 in flight (ring-5, depth-4 prefetch), B tap 0
  ATap A0 = ldA(0), A1 = ldA(1), A2 = ldA(2), A3 = ldA(3), A4;
  BTap B0 = ldB(0), B1;

  // invariant at iter k: slot k%5 holds tap k, B(k&1) holds tap k.
  // prefetch slot (k+4)%5 == (k-1)%5 was consumed last iteration.
  static_for<0, KT>([&]<int k>() {
    if constexpr (k + 4 < KT) {
      ATap tmp = ldA(k + 4);
      constexpr int s = (k + 4) % 5;
      if constexpr (s == 0) A0 = tmp;
      else if constexpr (s == 1) A1 = tmp;
      else if constexpr (s == 2) A2 = tmp;
      else if constexpr (s == 3) A3 = tmp;
      else A4 = tmp;
    }
    if constexpr (k + 1 < KT) {
      BTap tmp = ldB(k + 1);
      if constexpr (((k + 1) & 1) == 0) B0 = tmp; else B1 = tmp;
    }
    constexpr int c = k % 5;
    if constexpr (c == 0) { if constexpr ((k & 1) == 0) compute(A0, B0); else compute(A0, B1); }
    else if constexpr (c == 1) { if constexpr ((k & 1) == 0) compute(A1, B0); else compute(A1, B1); }
    else if constexpr (c == 2) { if constexpr ((k & 1) == 0) compute(A2, B0); else compute(A2, B1); }
    else if constexpr (c == 3) { if constexpr ((k & 1) == 0) compute(A3, B0); else compute(A3, B1); }
    else { if constexpr ((k & 1) == 0) compute(A4, B0); else compute(A4, B1); }
  });

  // epilogue: store h + fused per-channel stats
  // C/D (32x32): col = lane&31, row = (reg&3) + 8*(reg>>2) + 4*(lane>>5)
  const int orow0 = wbase + (hh << 2);
  float s0 = 0.f, q0 = 0.f, s1 = 0.f, q1 = 0.f;
#pragma unroll
  for (int reg = 0; reg < 16; ++reg) {
    int row = orow0 + (reg & 3) + 8 * (reg >> 2);
    float v0 = acc0[reg], v1 = acc1[reg];
    if (OBF16) {
      ushort_t* ho = (ushort_t*)houtv;
      ho[row * 64 + r31] = f2bf(v0);
      ho[row * 64 + 32 + r31] = f2bf(v1);
    } else {
      float* ho = (float*)houtv;
      ho[row * 64 + r31] = v0;
      ho[row * 64 + 32 + r31] = v1;
    }
    s0 += v0; q0 += v0 * v0;
    s1 += v1; q1 += v1 * v1;
  }
  s0 += __shfl_xor(s0, 32, 64); q0 += __shfl_xor(q0, 32, 64);
  s1 += __shfl_xor(s1, 32, 64); q1 += __shfl_xor(q1, 32, 64);
  if (hh == 0) {
    red[0][w][r31] = s0; red[0][w][32 + r31] = s1;
    red[1][w][r31] = q0; red[1][w][32 + r31] = q1;
  }
  __syncthreads();   // only barrier in the kernel
  if (t < 128) {
    int which = t >> 6, c = t & 63;
    float v = red[which][0][c] + red[which][1][c] + red[which][2][c] + red[which][3][c];
    atomicAdd((which ? gsq : gsum) + c, v);
  }
}

// BN1 (inline params from raw stats) + ReLU on bf16 h1, writes bf16 for conv2's gather
__global__ __launch_bounds__(256) void k_bn_relu(const ushort_t* __restrict__ h,
                                                 const float* __restrict__ gsum,
                                                 const float* __restrict__ gsq,
                                                 const float* __restrict__ gamma,
                                                 const float* __restrict__ beta,
                                                 ushort_t* __restrict__ ob) {
  __shared__ float sc[64], sh[64];
  int t = threadIdx.x;
  if (t < 64) {
    float mean = gsum[t] * (1.f / NV);
    float var = gsq[t] * (1.f / NV) - mean * mean;
    float rs = rsqrtf(var + 1e-5f);
    float s = gamma[t] * rs;
    sc[t] = s;
    sh[t] = beta[t] - mean * s;
  }
  __syncthreads();
  int i = blockIdx.x * 256 + t;    // uint4 index = 8 bf16
  int c0 = (i & 7) * 8;
  uint4 v = ((const uint4*)h)[i];
  const ushort_t* pu = (const ushort_t*)&v;
  uint4 o;
  ushort_t* po = (ushort_t*)&o;
#pragma unroll
  for (int n = 0; n < 8; ++n)
    po[n] = f2bf(fmaxf(0.f, b2f(pu[n]) * sc[c0 + n] + sh[c0 + n]));
  ((uint4*)ob)[i] = o;
}

// BN2 (inline params) + residual + ReLU, fp32 out
__global__ __launch_bounds__(256) void k_final(const float* __restrict__ h,
                                               const float* __restrict__ x,
                                               const float* __restrict__ gsum,
                                               const float* __restrict__ gsq,
                                               const float* __restrict__ gamma,
                                               const float* __restrict__ beta,
                                               float* __restrict__ out) {
  __shared__ float sc[64], sh[64];
  int t = threadIdx.x;
  if (t < 64) {
    float mean = gsum[t] * (1.f / NV);
    float var = gsq[t] * (1.f / NV) - mean * mean;
    float rs = rsqrtf(var + 1e-5f);
    float s = gamma[t] * rs;
    sc[t] = s;
    sh[t] = beta[t] - mean * s;
  }
  __syncthreads();
  int i = blockIdx.x * 256 + t;
  int c0 = (i << 2) & 63;
  float4 v = ((const float4*)h)[i];
  float4 xv = ((const float4*)x)[i];
  float4 o;
  o.x = fmaxf(0.f, v.x * sc[c0]     + sh[c0]     + xv.x);
  o.y = fmaxf(0.f, v.y * sc[c0 + 1] + sh[c0 + 1] + xv.y);
  o.z = fmaxf(0.f, v.z * sc[c0 + 2] + sh[c0 + 2] + xv.z);
  o.w = fmaxf(0.f, v.w * sc[c0 + 3] + sh[c0 + 3] + xv.w);
  ((float4*)out)[i] = o;
}

extern "C" void kernel_launch(void* const* d_in, const int* in_sizes, int n_in,
                              void* d_out, int out_size, void* d_ws, size_t ws_size,
                              hipStream_t stream) {
  const float* x   = (const float*)d_in[0];
  const int*   nbr = (const int*)d_in[1];
  const float* W1  = (const float*)d_in[2];
  const float* g1  = (const float*)d_in[3];
  const float* b1  = (const float*)d_in[4];
  const float* W2  = (const float*)d_in[5];
  const float* g2  = (const float*)d_in[6];
  const float* b2  = (const float*)d_in[7];
  float* out = (float*)d_out;
  char* ws = (char*)d_ws;

  // workspace layout (bytes, 256-aligned), total ~42.8 MB (+2KB stats/zero pad)
  ushort_t* xb     = (ushort_t*)(ws);               // 8,388,608
  ushort_t* h1pre  = (ushort_t*)(ws + 8388608);     // 8,388,608 (bf16, pre-BN)
  ushort_t* h1post = (ushort_t*)(ws + 16777216);    // 8,388,608 (bf16, post-BN+ReLU)
  ushort_t* Wf1    = (ushort_t*)(ws + 25165824);    // 442,368
  ushort_t* Wf2    = (ushort_t*)(ws + 25608192);    // 442,368
  float*    h2raw  = (float*)(ws + 26050560);       // 16,777,216
  float*    statsp = (float*)(ws + 42827776);       // 512 floats (stats + zero row)
  float *gsum1 = statsp, *gsq1 = statsp + 64, *gsum2 = statsp + 128, *gsq2 = statsp + 192;
  const ushort_t* zrow = (const ushort_t*)(statsp + 256);  // 1KB of zeros

  k_prep<<<5824, 256, 0, stream>>>(x, W1, W2, xb, Wf1, Wf2, statsp);

  k_conv<true><<<512, 256, 0, stream>>>(xb, nbr, Wf1, zrow, (void*)h1pre, gsum1, gsq1);
  k_bn_relu<<<2048, 256, 0, stream>>>(h1pre, gsum1, gsq1, g1, b1, h1post);
  k_conv<false><<<512, 256, 0, stream>>>(h1post, nbr, Wf2, zrow, (void*)h2raw, gsum2, gsq2);

  k_final<<<4096, 256, 0, stream>>>(h2raw, x, gsum2, gsq2, g2, b2, out);
}

// Round 5
// 181.620 us; speedup vs baseline: 1.1534x; 1.0137x over previous
//
#include <hip/hip_runtime.h>

typedef unsigned short ushort_t;
using bf16x8 = __attribute__((ext_vector_type(8))) short;
using f32x16 = __attribute__((ext_vector_type(16))) float;

#define KT 27
#define NV 65536

__device__ inline unsigned short f2bf(float f) {
  unsigned int u = __builtin_bit_cast(unsigned int, f);
  u += 0x7fffu + ((u >> 16) & 1u);
  return (unsigned short)(u >> 16);
}
__device__ inline float b2f(ushort_t u) {
  unsigned int x = ((unsigned int)u) << 16;
  return __builtin_bit_cast(float, x);
}

// compile-time loop: every iteration index is constexpr.
template <int I, int N, typename F>
__device__ __forceinline__ void static_for(F&& f) {
  if constexpr (I < N) {
    f.template operator()<I>();
    static_for<I + 1, N>(static_cast<F&&>(f));
  }
}

// merged prep: statsp+zrow zero (block 0), x fp32->bf16 (blocks 0..4095),
// W1,W2 [k][c][d] -> per-lane MFMA B frags (blocks 4096..5823)
// Wf[(k*8 + ks*2 + ct)*512 + l*8 + j] = bf16(W[k][ks*16 + (l>>5)*8 + j][ct*32 + (l&31)])
__global__ __launch_bounds__(256) void k_prep(const float* __restrict__ x,
                                              const float* __restrict__ W1,
                                              const float* __restrict__ W2,
                                              ushort_t* __restrict__ xb,
                                              ushort_t* __restrict__ Wf1,
                                              ushort_t* __restrict__ Wf2,
                                              float* __restrict__ statsp) {
  int b = blockIdx.x;
  int t = threadIdx.x;
  if (b == 0) {                    // 256 stats floats + 256 floats of zero-row pad
    statsp[t] = 0.f;               // convs run after this dispatch
    statsp[256 + t] = 0.f;         // zrow: gather target for inactive taps
  }
  if (b < 4096) {
    int i = b * 256 + t;  // float4 index
    float4 v = ((const float4*)x)[i];
    ushort4 o;
    o.x = f2bf(v.x); o.y = f2bf(v.y); o.z = f2bf(v.z); o.w = f2bf(v.w);
    ((ushort4*)xb)[i] = o;
  } else {
    int e = (b - 4096) * 256 + t;  // < 442368
    const float* W = W1; ushort_t* Wf = Wf1;
    if (e >= 221184) { e -= 221184; W = W2; Wf = Wf2; }
    int j = e & 7, l = (e >> 3) & 63, u = (e >> 9) & 7, k = e >> 12;
    int ks = u >> 1, ct = u & 1;
    int c = ks * 16 + (l >> 5) * 8 + j;
    int d = ct * 32 + (l & 31);
    Wf[e] = f2bf(W[(k << 12) + (c << 6) + d]);
  }
}

// Gather-GEMM conv, 32x32x16 MFMA, BARRIER-FREE K-loop, ZERO A-staging.
// block = 256 thr = 4 fully independent waves; wave w owns voxels wbase..wbase+31.
// A fragments gathered DIRECTLY from global into MFMA layout (one 16B load per
// lane per k-slice); B frags register-direct from pre-swizzled Wf (L2-hot).
// R4 fix: amdgpu_waves_per_eu(2,2) gives the 256-VGPR budget (grid-capped at
// 2 waves/EU anyway). R4 result: VGPR only 88 -> scheduler STILL sank loads
// to their uses (depth-1 pipeline, latency-serial, 47.5us).
// R5 fix: __builtin_amdgcn_sched_barrier(0) between the load-issue section
// and the MFMA section of each K-iteration. Loads cannot sink past the
// barrier into/past compute; their values live across >=4 barriers, forcing
// the allocator to hold the ring in VGPRs. Tell: VGPR_Count ~200.
// Pipeline: A prefetched 4 taps ahead (ring-5 named SSA slots), B dbuf.
// Only LDS: per-wave rulebook rows + stats reduce (15.9 KB/block).
template<bool OBF16>
__global__ __launch_bounds__(256)
__attribute__((amdgpu_waves_per_eu(2, 2)))
void k_conv(const ushort_t* __restrict__ src,  // [N][64] bf16
            const int* __restrict__ nbr,       // [N][27]
            const ushort_t* __restrict__ Wf,
            const ushort_t* __restrict__ zrow, // 128B of zeros
            void* __restrict__ houtv,          // [N][64]
            float* __restrict__ gsum,
            float* __restrict__ gsq) {
  __shared__ int nb_l[4][32 * KT];                 // per-wave rulebook rows, 13.8 KB
  __shared__ float red[2][4][64];                  // stats reduce, 2 KB

  const int t = threadIdx.x;
  const int lane = t & 63;
  const int w = t >> 6;
  const int hh = lane >> 5;
  const int r31 = lane & 31;
  const int wbase = blockIdx.x * 128 + w * 32;

  int* nbw = &nb_l[w][0];
  {
    const int* nbg = nbr + wbase * KT;
    for (int e = lane; e < 32 * KT; e += 64) nbw[e] = nbg[e];  // wave-local: no barrier
  }

  f32x16 acc0 = {0,0,0,0,0,0,0,0,0,0,0,0,0,0,0,0};
  f32x16 acc1 = {0,0,0,0,0,0,0,0,0,0,0,0,0,0,0,0};

  struct ATap { bf16x8 v0, v1, v2, v3; };              // 16 VGPRs, by-value only
  struct BTap { bf16x8 b0, b1, b2, b3, b4, b5, b6, b7; };  // 32 VGPRs, by-value only

  const ushort_t* srcl = src + hh * 8;   // lane's K-half offset folded into base
  const ushort_t* zl = zrow + hh * 8;

  // A frag for tap k: row r31, channels ks*16 + hh*8 .. +8  (one dwordx4 each)
  auto ldA = [&](int k) -> ATap {
    int idx = nbw[r31 * KT + k];
    const ushort_t* p = (idx >= 0) ? (srcl + ((long)idx << 6)) : zl;
    ATap a;
    a.v0 = *(const bf16x8*)(p);
    a.v1 = *(const bf16x8*)(p + 16);
    a.v2 = *(const bf16x8*)(p + 32);
    a.v3 = *(const bf16x8*)(p + 48);
    return a;
  };
  auto ldB = [&](int k) -> BTap {
    const ushort_t* p = Wf + k * 4096 + lane * 8;
    BTap b;
    b.b0 = *(const bf16x8*)(p);
    b.b1 = *(const bf16x8*)(p + 512);
    b.b2 = *(const bf16x8*)(p + 1024);
    b.b3 = *(const bf16x8*)(p + 1536);
    b.b4 = *(const bf16x8*)(p + 2048);
    b.b5 = *(const bf16x8*)(p + 2560);
    b.b6 = *(const bf16x8*)(p + 3072);
    b.b7 = *(const bf16x8*)(p + 3584);
    return b;
  };
  auto compute = [&](ATap a, BTap b) {
    acc0 = __builtin_amdgcn_mfma_f32_32x32x16_bf16(a.v0, b.b0, acc0, 0, 0, 0);
    acc1 = __builtin_amdgcn_mfma_f32_32x32x16_bf16(a.v0, b.b1, acc1, 0, 0, 0);
    acc0 = __builtin_amdgcn_mfma_f32_32x32x16_bf16(a.v1, b.b2, acc0, 0, 0, 0);
    acc1 = __builtin_amdgcn_mfma_f32_32x32x16_bf16(a.v1, b.b3, acc1, 0, 0, 0);
    acc0 = __builtin_amdgcn_mfma_f32_32x32x16_bf16(a.v2, b.b4, acc0, 0, 0, 0);
    acc1 = __builtin_amdgcn_mfma_f32_32x32x16_bf16(a.v2, b.b5, acc1, 0, 0, 0);
    acc0 = __builtin_amdgcn_mfma_f32_32x32x16_bf16(a.v3, b.b6, acc0, 0, 0, 0);
    acc1 = __builtin_amdgcn_mfma_f32_32x32x16_bf16(a.v3, b.b7, acc1, 0, 0, 0);
  };

  // prologue: A taps 0..3 in flight (ring-5, depth-4 prefetch), B tap 0
  ATap A0 = ldA(0), A1 = ldA(1), A2 = ldA(2), A3 = ldA(3), A4;
  BTap B0 = ldB(0), B1;

  // invariant at iter k: slot k%5 holds tap k, B(k&1) holds tap k.
  // prefetch slot (k+4)%5 == (k-1)%5 was consumed last iteration.
  // Per iteration: issue loads -> sched_barrier(0) -> MFMA tap k.
  static_for<0, KT>([&]<int k>() {
    if constexpr (k + 4 < KT) {
      ATap tmp = ldA(k + 4);
      constexpr int s = (k + 4) % 5;
      if constexpr (s == 0) A0 = tmp;
      else if constexpr (s == 1) A1 = tmp;
      else if constexpr (s == 2) A2 = tmp;
      else if constexpr (s == 3) A3 = tmp;
      else A4 = tmp;
    }
    if constexpr (k + 1 < KT) {
      BTap tmp = ldB(k + 1);
      if constexpr (((k + 1) & 1) == 0) B0 = tmp; else B1 = tmp;
    }
    __builtin_amdgcn_sched_barrier(0);   // loads above may NOT sink past here
    constexpr int c = k % 5;
    if constexpr (c == 0) { if constexpr ((k & 1) == 0) compute(A0, B0); else compute(A0, B1); }
    else if constexpr (c == 1) { if constexpr ((k & 1) == 0) compute(A1, B0); else compute(A1, B1); }
    else if constexpr (c == 2) { if constexpr ((k & 1) == 0) compute(A2, B0); else compute(A2, B1); }
    else if constexpr (c == 3) { if constexpr ((k & 1) == 0) compute(A3, B0); else compute(A3, B1); }
    else { if constexpr ((k & 1) == 0) compute(A4, B0); else compute(A4, B1); }
  });

  // epilogue: store h + fused per-channel stats
  // C/D (32x32): col = lane&31, row = (reg&3) + 8*(reg>>2) + 4*(lane>>5)
  const int orow0 = wbase + (hh << 2);
  float s0 = 0.f, q0 = 0.f, s1 = 0.f, q1 = 0.f;
#pragma unroll
  for (int reg = 0; reg < 16; ++reg) {
    int row = orow0 + (reg & 3) + 8 * (reg >> 2);
    float v0 = acc0[reg], v1 = acc1[reg];
    if (OBF16) {
      ushort_t* ho = (ushort_t*)houtv;
      ho[row * 64 + r31] = f2bf(v0);
      ho[row * 64 + 32 + r31] = f2bf(v1);
    } else {
      float* ho = (float*)houtv;
      ho[row * 64 + r31] = v0;
      ho[row * 64 + 32 + r31] = v1;
    }
    s0 += v0; q0 += v0 * v0;
    s1 += v1; q1 += v1 * v1;
  }
  s0 += __shfl_xor(s0, 32, 64); q0 += __shfl_xor(q0, 32, 64);
  s1 += __shfl_xor(s1, 32, 64); q1 += __shfl_xor(q1, 32, 64);
  if (hh == 0) {
    red[0][w][r31] = s0; red[0][w][32 + r31] = s1;
    red[1][w][r31] = q0; red[1][w][32 + r31] = q1;
  }
  __syncthreads();   // only barrier in the kernel
  if (t < 128) {
    int which = t >> 6, c = t & 63;
    float v = red[which][0][c] + red[which][1][c] + red[which][2][c] + red[which][3][c];
    atomicAdd((which ? gsq : gsum) + c, v);
  }
}

// BN1 (inline params from raw stats) + ReLU on bf16 h1, writes bf16 for conv2's gather
__global__ __launch_bounds__(256) void k_bn_relu(const ushort_t* __restrict__ h,
                                                 const float* __restrict__ gsum,
                                                 const float* __restrict__ gsq,
                                                 const float* __restrict__ gamma,
                                                 const float* __restrict__ beta,
                                                 ushort_t* __restrict__ ob) {
  __shared__ float sc[64], sh[64];
  int t = threadIdx.x;
  if (t < 64) {
    float mean = gsum[t] * (1.f / NV);
    float var = gsq[t] * (1.f / NV) - mean * mean;
    float rs = rsqrtf(var + 1e-5f);
    float s = gamma[t] * rs;
    sc[t] = s;
    sh[t] = beta[t] - mean * s;
  }
  __syncthreads();
  int i = blockIdx.x * 256 + t;    // uint4 index = 8 bf16
  int c0 = (i & 7) * 8;
  uint4 v = ((const uint4*)h)[i];
  const ushort_t* pu = (const ushort_t*)&v;
  uint4 o;
  ushort_t* po = (ushort_t*)&o;
#pragma unroll
  for (int n = 0; n < 8; ++n)
    po[n] = f2bf(fmaxf(0.f, b2f(pu[n]) * sc[c0 + n] + sh[c0 + n]));
  ((uint4*)ob)[i] = o;
}

// BN2 (inline params) + residual + ReLU, fp32 out
__global__ __launch_bounds__(256) void k_final(const float* __restrict__ h,
                                               const float* __restrict__ x,
                                               const float* __restrict__ gsum,
                                               const float* __restrict__ gsq,
                                               const float* __restrict__ gamma,
                                               const float* __restrict__ beta,
                                               float* __restrict__ out) {
  __shared__ float sc[64], sh[64];
  int t = threadIdx.x;
  if (t < 64) {
    float mean = gsum[t] * (1.f / NV);
    float var = gsq[t] * (1.f / NV) - mean * mean;
    float rs = rsqrtf(var + 1e-5f);
    float s = gamma[t] * rs;
    sc[t] = s;
    sh[t] = beta[t] - mean * s;
  }
  __syncthreads();
  int i = blockIdx.x * 256 + t;
  int c0 = (i << 2) & 63;
  float4 v = ((const float4*)h)[i];
  float4 xv = ((const float4*)x)[i];
  float4 o;
  o.x = fmaxf(0.f, v.x * sc[c0]     + sh[c0]     + xv.x);
  o.y = fmaxf(0.f, v.y * sc[c0 + 1] + sh[c0 + 1] + xv.y);
  o.z = fmaxf(0.f, v.z * sc[c0 + 2] + sh[c0 + 2] + xv.z);
  o.w = fmaxf(0.f, v.w * sc[c0 + 3] + sh[c0 + 3] + xv.w);
  ((float4*)out)[i] = o;
}

extern "C" void kernel_launch(void* const* d_in, const int* in_sizes, int n_in,
                              void* d_out, int out_size, void* d_ws, size_t ws_size,
                              hipStream_t stream) {
  const float* x   = (const float*)d_in[0];
  const int*   nbr = (const int*)d_in[1];
  const float* W1  = (const float*)d_in[2];
  const float* g1  = (const float*)d_in[3];
  const float* b1  = (const float*)d_in[4];
  const float* W2  = (const float*)d_in[5];
  const float* g2  = (const float*)d_in[6];
  const float* b2  = (const float*)d_in[7];
  float* out = (float*)d_out;
  char* ws = (char*)d_ws;

  // workspace layout (bytes, 256-aligned), total ~42.8 MB (+2KB stats/zero pad)
  ushort_t* xb     = (ushort_t*)(ws);               // 8,388,608
  ushort_t* h1pre  = (ushort_t*)(ws + 8388608);     // 8,388,608 (bf16, pre-BN)
  ushort_t* h1post = (ushort_t*)(ws + 16777216);    // 8,388,608 (bf16, post-BN+ReLU)
  ushort_t* Wf1    = (ushort_t*)(ws + 25165824);    // 442,368
  ushort_t* Wf2    = (ushort_t*)(ws + 25608192);    // 442,368
  float*    h2raw  = (float*)(ws + 26050560);       // 16,777,216
  float*    statsp = (float*)(ws + 42827776);       // 512 floats (stats + zero row)
  float *gsum1 = statsp, *gsq1 = statsp + 64, *gsum2 = statsp + 128, *gsq2 = statsp + 192;
  const ushort_t* zrow = (const ushort_t*)(statsp + 256);  // 1KB of zeros

  k_prep<<<5824, 256, 0, stream>>>(x, W1, W2, xb, Wf1, Wf2, statsp);

  k_conv<true><<<512, 256, 0, stream>>>(xb, nbr, Wf1, zrow, (void*)h1pre, gsum1, gsq1);
  k_bn_relu<<<2048, 256, 0, stream>>>(h1pre, gsum1, gsq1, g1, b1, h1post);
  k_conv<false><<<512, 256, 0, stream>>>(h1post, nbr, Wf2, zrow, (void*)h2raw, gsum2, gsq2);

  k_final<<<4096, 256, 0, stream>>>(h2raw, x, gsum2, gsq2, g2, b2, out);
}